// Round 13
// baseline (509.599 us; speedup 1.0000x reference)
//
#include <hip/hip_runtime.h>
#include <hip/hip_bf16.h>

// RGCN classifier, MI355X. Round 13: XW eliminated. Fused per-layer kernel:
// block = 64 nodes; bins sorted by relation in-wave (ballot ranks, no atomics);
// 9 phases of {gather agg_r+1 into LDS dbuf || MFMA agg_r @ W_r}; self = phase 8
// via coalesced global_load_lds of own h rows; bias+relu epilogue (LDS-staged
// coalesced write); layer 2 fuses per-block max pool. Saves ~600 MB HBM traffic
// (XW was 151 MB write + 151 MB random read per layer).
// ws layout (bytes):
//   hb      @ 0        : 16,777,216  (h bf16 [node][128])
//   h1b     @ 16777216 : 16,777,216
//   Wt1c    @ 33554432 : 294,912     (bf16 [tile*128+n][k])
//   Wt2c    @ 33849344 : 294,912
//   cnt     @ 34144256 : 262,144
//   bins    @ 34406400 : 16,777,216  (uint [node][64]: rec = src<<3 | rel)
//   partial @ 51183616 : 524,288     (f32 [1024][128] pool partials)
// total ~51.7 MB

#define N_NODES 65536
#define N_EDGES 786432
#define DIM 128
#define N_GRAPHS 64

typedef unsigned int uint;
typedef unsigned short ushort;
typedef unsigned char uchar;
typedef __attribute__((ext_vector_type(8))) short short8;
typedef __attribute__((ext_vector_type(4))) float f32x4;

__device__ inline ushort f2b(float f) {
  uint u = __float_as_uint(f);
  u += 0x7fff + ((u >> 16) & 1);   // RNE
  return (ushort)(u >> 16);
}
__device__ inline float b2f(ushort h) { return __uint_as_float(((uint)h) << 16); }
__device__ inline float blo(uint v) { return __uint_as_float(v << 16); }
__device__ inline float bhi(uint v) { return __uint_as_float(v & 0xffff0000u); }

__device__ inline void gl_lds16(const void* g, void* l) {
  __builtin_amdgcn_global_load_lds(
      (const __attribute__((address_space(1))) unsigned int*)g,
      (__attribute__((address_space(3))) unsigned int*)l, 16, 0, 0);
}

// ---------------- conversions ----------------
__global__ __launch_bounds__(256) void f32_to_bf16_vec(const float* __restrict__ x,
                                                       ushort* __restrict__ y, int n4) {
  int i = blockIdx.x * 256 + threadIdx.x;
  if (i >= n4) return;
  float4 v = ((const float4*)x)[i];
  ushort4 o;
  o.x = f2b(v.x); o.y = f2b(v.y); o.z = f2b(v.z); o.w = f2b(v.w);
  ((ushort4*)y)[i] = o;
}

// Weights -> bf16 [tile*128+n][k] (tile 8 = W_self)
__global__ __launch_bounds__(256) void wconv_all(const float* __restrict__ W1,
                                                 const float* __restrict__ W1s,
                                                 const float* __restrict__ W2,
                                                 const float* __restrict__ W2s,
                                                 ushort* __restrict__ Wt1,
                                                 ushort* __restrict__ Wt2) {
  int b = blockIdx.x;  // 0..17
  const float* S;
  ushort* D;
  int tile;
  if (b < 9) { D = Wt1; tile = b; S = (b < 8) ? (W1 + (size_t)b * 16384) : W1s; }
  else       { D = Wt2; tile = b - 9; S = (tile < 8) ? (W2 + (size_t)tile * 16384) : W2s; }
  for (int i = threadIdx.x; i < 16384; i += 256) {
    int n = i >> 7, k = i & 127;
    D[((size_t)tile * 128 + n) * 128 + k] = f2b(S[k * 128 + n]);
  }
}

// ---------------- edge binning (XCD-sliced, rec = src<<3 | rel) ----------------
__global__ __launch_bounds__(256) void fill_bins_sliced(const int* __restrict__ src,
                                                        const int* __restrict__ dst,
                                                        const int* __restrict__ et,
                                                        int* __restrict__ cnt,
                                                        uint* __restrict__ bins) {
  int slice = blockIdx.x & 7;
  int e = (blockIdx.x >> 3) * 256 + threadIdx.x;
  if (e >= N_EDGES) return;
  int d = dst[e];
  if ((d >> 13) != slice) return;
  int r = atomicAdd(&cnt[d], 1);
  if (r < 64) bins[((size_t)d << 6) + r] = ((uint)src[e] << 3) | (uint)et[e];
}

// ---------------- fused RGCN layer ----------------
// gather agg for relation r (wave wv owns nodes [wv*16, wv*16+16))
__device__ __forceinline__ void gather_rel(int wv, int ln, int r,
                                           const uint* __restrict__ hw,
                                           const uint* sbin,
                                           const uchar (*soff)[16],
                                           char* ab) {
  for (int k = 0; k < 16; ++k) {
    int nl = wv * 16 + k;
    int s = __builtin_amdgcn_readfirstlane((int)soff[nl][r]);
    int e = __builtin_amdgcn_readfirstlane((int)soff[nl][r + 1]);
    float ax = 0.f, ay = 0.f;
    for (int j = s; j < e; ++j) {
      uint rec = sbin[nl * 64 + j];                 // LDS broadcast read
      uint v = hw[(size_t)(rec >> 3) * 64 + ln];    // 256B coalesced row read
      ax += blo(v); ay += bhi(v);
    }
    uint o = (uint)f2b(ax) | ((uint)f2b(ay) << 16); // zeros when s==e
    *(uint*)(ab + nl * 256 + ((ln * 4) ^ ((nl & 15) << 4))) = o;
  }
}

template <bool POOL>
__global__ __launch_bounds__(256) void rgcn_layer(const ushort* __restrict__ hin,
                                                  const uint* __restrict__ bins,
                                                  const int* __restrict__ cnt,
                                                  const ushort* __restrict__ Wt,
                                                  const float* __restrict__ bias,
                                                  ushort* __restrict__ hout,
                                                  float* __restrict__ partial) {
  __shared__ uint sbin[64 * 64];            // rel-sorted recs, 16 KB
  __shared__ uchar soff[64][16];            // rel starts [0..8]
  __shared__ char agg[2][16384];            // [64][256B] bf16, XOR-swizzled

  const int blk = blockIdx.x, nb = blk * 64;
  const int tid = threadIdx.x, wv = tid >> 6, ln = tid & 63;
  const int lr = ln & 15, kq = ln >> 4;
  const uint* hw = (const uint*)hin;
  unsigned long long lt = (1ull << ln) - 1ull;

  // ---- sort this block's bins by relation (wave per 16 nodes)
  for (int k = 0; k < 16; ++k) {
    int nl = wv * 16 + k;
    int node = nb + nl;
    int ne = cnt[node];
    if (ne > 64) ne = 64;
    uint rec = bins[((size_t)node << 6) + ln];
    bool valid = ln < ne;
    int key = (int)(rec & 7u);
    unsigned long long mymask = 0ull;
    int myoff = 0, run = 0;
#pragma unroll
    for (int r = 0; r < 8; ++r) {
      unsigned long long mr = __ballot(valid && key == r);
      if (key == r) { mymask = mr; myoff = run; }
      if (ln == r) soff[nl][r] = (uchar)run;
      run += __popcll(mr);
    }
    if (ln == 8) soff[nl][8] = (uchar)run;
    if (valid) sbin[nl * 64 + myoff + __popcll(mymask & lt)] = rec;
  }
  __syncthreads();

  f32x4 acc[4][2];
#pragma unroll
  for (int m = 0; m < 4; ++m)
#pragma unroll
    for (int n = 0; n < 2; ++n) acc[m][n] = (f32x4){0.f, 0.f, 0.f, 0.f};

  // prolog: agg for relation 0
  gather_rel(wv, ln, 0, hw, sbin, soff, agg[0]);
  __syncthreads();

  for (int r = 0; r < 9; ++r) {
    char* cur = agg[r & 1];
    char* nxt = agg[(r & 1) ^ 1];
    // b-frags for W_r straight from global (L2-resident, 295 KB total)
    short8 b[2][4];
#pragma unroll
    for (int n = 0; n < 2; ++n) {
      const ushort* wrow = Wt + ((size_t)(r * 128 + wv * 32 + n * 16 + lr)) * 128;
#pragma unroll
      for (int k2 = 0; k2 < 4; ++k2)
        b[n][k2] = *(const short8*)(wrow + k2 * 32 + kq * 8);
    }
    // prep next phase's agg (overlaps this phase's MFMA consumption)
    if (r < 7) {
      gather_rel(wv, ln, r + 1, hw, sbin, soff, nxt);
    } else if (r == 7) {
      // self tile: coalesced global_load_lds of own h rows, pre-swizzled source
      const char* hbase = (const char*)(hin + (size_t)nb * 128);
#pragma unroll
      for (int it = 0; it < 4; ++it) {
        int p = it * 4096 + tid * 16;
        int row = p >> 8, inb = p & 255;
        gl_lds16(hbase + row * 256 + (inb ^ ((row & 15) << 4)), nxt + p);
      }
    }
    // MFMA: acc += agg_r @ W_r
#pragma unroll
    for (int k2 = 0; k2 < 4; ++k2) {
      const int kb = k2 * 64 + kq * 16;
      short8 a[4];
#pragma unroll
      for (int m = 0; m < 4; ++m) {
        int row = m * 16 + lr;
        a[m] = *(const short8*)(cur + row * 256 + (kb ^ ((row & 15) << 4)));
      }
#pragma unroll
      for (int m = 0; m < 4; ++m)
#pragma unroll
        for (int n = 0; n < 2; ++n)
          acc[m][n] = __builtin_amdgcn_mfma_f32_16x16x32_bf16(a[m], b[n][k2], acc[m][n], 0, 0, 0);
    }
    asm volatile("s_waitcnt vmcnt(0)" ::: "memory");
    __syncthreads();
  }

  // ---- epilogue: bias + relu -> LDS stage (swizzled) -> coalesced write / pool
  char* ob = agg[0];
  float bvals[2];
#pragma unroll
  for (int n = 0; n < 2; ++n) bvals[n] = bias[wv * 32 + n * 16 + lr];
#pragma unroll
  for (int m = 0; m < 4; ++m) {
#pragma unroll
    for (int n = 0; n < 2; ++n) {
      int colb = (wv * 32 + n * 16 + lr) * 2;
#pragma unroll
      for (int e = 0; e < 4; ++e) {
        int row = m * 16 + kq * 4 + e;
        float v = fmaxf(acc[m][n][e] + bvals[n], 0.f);
        *(ushort*)(ob + ((row * 256 + colb) ^ ((row & 15) << 4))) = f2b(v);
      }
    }
  }
  __syncthreads();
  if (!POOL) {
    char* dst = (char*)hout + (size_t)nb * 256;
#pragma unroll
    for (int it = 0; it < 4; ++it) {
      int p = it * 4096 + tid * 16;
      int row = p >> 8, inb = p & 255;
      short8 v = *(const short8*)(ob + row * 256 + (inb ^ ((row & 15) << 4)));
      *(short8*)(dst + (size_t)row * 256 + inb) = v;
    }
  } else {
    if (tid < 128) {
      float m = 0.f;
      for (int row = 0; row < 64; ++row)
        m = fmaxf(m, b2f(*(const ushort*)(ob + ((row * 256 + tid * 2) ^ ((row & 15) << 4)))));
      partial[(size_t)blk * 128 + tid] = m;
    }
  }
}

// ---------------- classifier: pooled = max over 16 block-partials ----------------
__global__ __launch_bounds__(128) void classify(const float* __restrict__ partial,
                                                const float* __restrict__ Wc,
                                                const float* __restrict__ bc,
                                                float* __restrict__ out) {
  __shared__ float pooled[128];
  int g = blockIdx.x, t = threadIdx.x;
  const float* p = partial + (size_t)g * 16 * 128;
  float m = 0.f;
#pragma unroll
  for (int i = 0; i < 16; ++i) m = fmaxf(m, p[i * 128 + t]);
  pooled[t] = m;
  __syncthreads();
  if (t < 10) {
    float s = bc[t];
    for (int d = 0; d < DIM; ++d) s += pooled[d] * Wc[d * 10 + t];
    out[g * 10 + t] = s;
  }
}

extern "C" void kernel_launch(void* const* d_in, const int* in_sizes, int n_in,
                              void* d_out, int out_size, void* d_ws, size_t ws_size,
                              hipStream_t stream) {
  const float* h       = (const float*)d_in[0];
  const float* W1      = (const float*)d_in[1];
  const float* W1_self = (const float*)d_in[2];
  const float* b1      = (const float*)d_in[3];
  const float* W2      = (const float*)d_in[4];
  const float* W2_self = (const float*)d_in[5];
  const float* b2      = (const float*)d_in[6];
  const float* Wc      = (const float*)d_in[7];
  const float* bc      = (const float*)d_in[8];
  const int* src   = (const int*)d_in[9];
  const int* dst   = (const int*)d_in[10];
  const int* etype = (const int*)d_in[11];
  float* out = (float*)d_out;

  char* ws = (char*)d_ws;
  ushort* hb      = (ushort*)(ws);
  ushort* h1b     = (ushort*)(ws + 16777216);
  ushort* Wt1c    = (ushort*)(ws + 33554432);
  ushort* Wt2c    = (ushort*)(ws + 33849344);
  int*    cnt     = (int*)(ws + 34144256);
  uint*   bins    = (uint*)(ws + 34406400);
  float*  partial = (float*)(ws + 51183616);

  const int n4_h = N_NODES * DIM / 4;        // 2,097,152
  const int g_h = n4_h / 256;                // 8192
  const int g_edge = (N_EDGES + 255) / 256;  // 3072
  const int g_sliced = g_edge * 8;           // 24576
  const int g_layer = N_NODES / 64;          // 1024

  // --- prep ---
  hipMemsetAsync(cnt, 0, N_NODES * sizeof(int), stream);
  f32_to_bf16_vec<<<g_h, 256, 0, stream>>>(h, hb, n4_h);
  wconv_all<<<18, 256, 0, stream>>>(W1, W1_self, W2, W2_self, Wt1c, Wt2c);
  fill_bins_sliced<<<g_sliced, 256, 0, stream>>>(src, dst, etype, cnt, bins);

  // --- layers (fused gather+GEMM, no XW materialization) ---
  rgcn_layer<false><<<g_layer, 256, 0, stream>>>(hb, bins, cnt, Wt1c, b1, h1b, partial);
  rgcn_layer<true><<<g_layer, 256, 0, stream>>>(h1b, bins, cnt, Wt2c, b2, h1b, partial);

  // --- classify ---
  classify<<<N_GRAPHS, 128, 0, stream>>>(partial, Wc, bc, out);

  (void)in_sizes; (void)n_in; (void)out_size; (void)ws_size;
}

// Round 14
// 256.457 us; speedup vs baseline: 1.9871x; 1.9871x over previous
//
#include <hip/hip_runtime.h>
#include <hip/hip_bf16.h>

// RGCN classifier, MI355X. Round 14: round-12 structure; fill shrunk to 256
// persistent blocks (1/CU) interleaved 1:18 with gemm1. Fill is pinned by XCD
// atomic throughput (98304 atomics/XCD ~= 41us regardless of wave count), so
// giving it 1/4 of slots instead of 4/7 lets gemm1 run at ~3/4 speed under it.
// Gather grid XCD-swizzled to match bins slicing. Cores frozen from round 12.
// ws layout (bytes):
//   XW      @ 0          : 65536*1152*2 = 150,994,944  (bf16 [node][1152])
//   hb      @ 150994944  : 16,777,216   (h bf16)
//   h1b     @ 167772160  : 16,777,216
//   Wt1c    @ 184549376  : 294,912      (bf16 [tile*128+n][k])
//   Wt2c    @ 184844288  : 294,912
//   cnt     @ 185139200  : 262,144      (int per node; doubles as degree)
//   bins    @ 185401344  : 16,777,216   (uint [node][64] edge records)
//   partial2@ 202178560  : 4,194,304    (bf16 [16384][128] pool partials)
// total ~206.4 MB

#define N_NODES 65536
#define N_EDGES 786432
#define DIM 128
#define NT 9
#define XW_LD (NT * DIM) /* 1152 */
#define N_GRAPHS 64
#define G_GEMM 4608
#define G_FUSED 4864   /* per XCD: 608 = 576 gemm + 32 fill, interleaved 1:18 */

typedef unsigned int uint;
typedef unsigned short ushort;
typedef __attribute__((ext_vector_type(8))) short short8;
typedef __attribute__((ext_vector_type(4))) float f32x4;

__device__ inline ushort f2b(float f) {
  uint u = __float_as_uint(f);
  u += 0x7fff + ((u >> 16) & 1);   // RNE
  return (ushort)(u >> 16);
}
__device__ inline float b2f(ushort h) { return __uint_as_float(((uint)h) << 16); }
__device__ inline float blo(uint v) { return __uint_as_float(v << 16); }
__device__ inline float bhi(uint v) { return __uint_as_float(v & 0xffff0000u); }

__device__ inline void gl_lds16(const void* g, void* l) {
  __builtin_amdgcn_global_load_lds(
      (const __attribute__((address_space(1))) unsigned int*)g,
      (__attribute__((address_space(3))) unsigned int*)l, 16, 0, 0);
}

// ---------------- conversions ----------------
__global__ __launch_bounds__(256) void f32_to_bf16_vec(const float* __restrict__ x,
                                                       ushort* __restrict__ y, int n4) {
  int i = blockIdx.x * 256 + threadIdx.x;
  if (i >= n4) return;
  float4 v = ((const float4*)x)[i];
  ushort4 o;
  o.x = f2b(v.x); o.y = f2b(v.y); o.z = f2b(v.z); o.w = f2b(v.w);
  ((ushort4*)y)[i] = o;
}

// Weights -> bf16 [tile*128+n][k] (B^T tiles, contiguous per output-col tile)
__global__ __launch_bounds__(256) void wconv_all(const float* __restrict__ W1,
                                                 const float* __restrict__ W1s,
                                                 const float* __restrict__ W2,
                                                 const float* __restrict__ W2s,
                                                 ushort* __restrict__ Wt1,
                                                 ushort* __restrict__ Wt2) {
  int b = blockIdx.x;  // 0..17
  const float* S;
  ushort* D;
  int tile;
  if (b < 9) { D = Wt1; tile = b; S = (b < 8) ? (W1 + (size_t)b * 16384) : W1s; }
  else       { D = Wt2; tile = b - 9; S = (tile < 8) ? (W2 + (size_t)tile * 16384) : W2s; }
  for (int i = threadIdx.x; i < 16384; i += 256) {
    int n = i >> 7, k = i & 127;
    D[((size_t)tile * 128 + n) * 128 + k] = f2b(S[k * 128 + n]);
  }
}

// ---------------- GEMM body: 128x128 tile, BK=64 x 2 phases, 32KB LDS ----------------
// tile in [0,4608): bm = tile/9, bn = tile%9. LDS-staged coalesced C epilogue.
// 4 blocks/CU -> acc fits the unified VGPR/AGPR budget (no spill).
__device__ __forceinline__ void gemm_body(const ushort* __restrict__ A,
                                          const ushort* __restrict__ Bt,
                                          ushort* __restrict__ C, int ldc,
                                          int tile, char* lds) {
  const int bm = tile / 9, bn = tile % 9;
  const char* Ag = (const char*)(A + (size_t)bm * 128 * 128);
  const char* Bg = (const char*)(Bt + (size_t)bn * 128 * 128);
  const int tid = threadIdx.x, wv = tid >> 6, ln = tid & 63;
  const int wm = wv >> 1, wn = wv & 1, lr = ln & 15, kq = ln >> 4;

  f32x4 acc[4][4];
#pragma unroll
  for (int m = 0; m < 4; ++m)
#pragma unroll
    for (int n = 0; n < 4; ++n) acc[m][n] = (f32x4){0.f, 0.f, 0.f, 0.f};

#pragma unroll
  for (int kt = 0; kt < 2; ++kt) {
    if (kt) __syncthreads();                  // prior phase's reads done
#pragma unroll
    for (int it = 0; it < 4; ++it) {
      int chunk = it * 4096 + wv * 1024;      // wave-uniform LDS base, 16KB total
      int p = chunk + ln * 16;                // linear lds byte pos
      int row = p >> 7, inb = p & 127;        // 128B rows
      int sw = inb ^ ((row & 7) << 4);        // pre-swizzled global source
      size_t gb = (size_t)row * 256 + (size_t)kt * 128 + sw;
      gl_lds16(Ag + gb, lds + chunk);
      gl_lds16(Bg + gb, lds + 16384 + chunk);
    }
    asm volatile("s_waitcnt vmcnt(0)" ::: "memory");
    __syncthreads();
#pragma unroll
    for (int k2 = 0; k2 < 2; ++k2) {
      const int kb = k2 * 64 + kq * 16;
      short8 a[4], b[4];
#pragma unroll
      for (int m = 0; m < 4; ++m) {
        int row = wm * 64 + m * 16 + lr;
        a[m] = *(const short8*)(lds + ((row * 128 + kb) ^ ((row & 7) << 4)));
      }
#pragma unroll
      for (int n = 0; n < 4; ++n) {
        int col = wn * 64 + n * 16 + lr;
        b[n] = *(const short8*)(lds + 16384 + ((col * 128 + kb) ^ ((col & 7) << 4)));
      }
#pragma unroll
      for (int m = 0; m < 4; ++m)
#pragma unroll
        for (int n = 0; n < 4; ++n)
          acc[m][n] = __builtin_amdgcn_mfma_f32_16x16x32_bf16(a[m], b[n], acc[m][n], 0, 0, 0);
    }
  }

  // ---- epilogue: acc -> LDS bf16 tile [128][256B] (swizzled), then coalesced write
  __syncthreads();  // all stage-buffer reads complete before reuse
#pragma unroll
  for (int m = 0; m < 4; ++m) {
    int rb0 = wm * 64 + m * 16 + kq * 4;
#pragma unroll
    for (int n = 0; n < 4; ++n) {
      int col = wn * 64 + n * 16 + lr;
#pragma unroll
      for (int e = 0; e < 4; ++e) {
        int row = rb0 + e;
        int off = (row * 256 + col * 2) ^ ((row & 7) << 4);
        *(ushort*)(lds + off) = f2b(acc[m][n][e]);
      }
    }
  }
  __syncthreads();
  char* Cg = (char*)C + (size_t)(bm * 128) * (size_t)ldc * 2 + (size_t)bn * 256;
#pragma unroll
  for (int it = 0; it < 8; ++it) {
    int p = it * 4096 + tid * 16;
    int row = p >> 8, inb = p & 255;
    short8 v = *(const short8*)(lds + row * 256 + (inb ^ ((row & 7) << 4)));
    *(short8*)(Cg + (size_t)row * (size_t)ldc * 2 + inb) = v;
  }
}

// layer-2 GEMM (standalone): XCD swizzle = each XCD owns 64 contiguous bm x 9 bn
__global__ __launch_bounds__(256, 4) void gemm_bk64(const ushort* __restrict__ A,
                                                    const ushort* __restrict__ Bt,
                                                    ushort* __restrict__ C, int ldc) {
  __shared__ char lds[32768];
  gemm_body(A, Bt, C, ldc, (blockIdx.x & 7) * 576 + (blockIdx.x >> 3), lds);
}

// layer-1 GEMM + fill, interleaved 1:18 per XCD. Fill = 32 blocks/XCD (1 per CU,
// occupying 1/4 slots); each scans edge chunk q (24576 edges, 24 int4 iters per
// thread) keeping slice==xcd (dst in [xcd*8192,(xcd+1)*8192) -> cnt/bins slice
// L2-local). Fill is XCD-atomic-throughput-pinned (~41us) and hides under the
// gemm, which now runs in 3/4 of the slots.
__global__ __launch_bounds__(256, 4) void gemm1_fill(const ushort* __restrict__ A,
                                                     const ushort* __restrict__ Bt,
                                                     ushort* __restrict__ C, int ldc,
                                                     const int* __restrict__ src,
                                                     const int* __restrict__ dst,
                                                     const int* __restrict__ et,
                                                     int* __restrict__ cnt,
                                                     uint* __restrict__ bins) {
  __shared__ char lds[32768];
  const int bid = blockIdx.x;            // 4864
  const int xcd = bid & 7, s = bid >> 3; // s in [0,608)
  const int q = s / 19, r = s % 19;      // q in [0,32)
  if (r != 0) {
    gemm_body(A, Bt, C, ldc, xcd * 576 + q * 18 + (r - 1), lds);
    return;
  }
  const int tid = threadIdx.x;
#pragma unroll 2
  for (int it = 0; it < 24; ++it) {
    int e0 = q * 24576 + it * 1024 + tid * 4;
    int4 d4 = *(const int4*)(dst + e0);
    int4 s4 = *(const int4*)(src + e0);
    int4 t4 = *(const int4*)(et + e0);
    uint r0 = (uint)s4.x * 576u + (uint)t4.x * 64u;
    uint r1 = (uint)s4.y * 576u + (uint)t4.y * 64u;
    uint r2 = (uint)s4.z * 576u + (uint)t4.z * 64u;
    uint r3 = (uint)s4.w * 576u + (uint)t4.w * 64u;
    if ((d4.x >> 13) == xcd) {
      int rk = atomicAdd(&cnt[d4.x], 1);
      if (rk < 64) bins[((size_t)d4.x << 6) + rk] = r0;
    }
    if ((d4.y >> 13) == xcd) {
      int rk = atomicAdd(&cnt[d4.y], 1);
      if (rk < 64) bins[((size_t)d4.y << 6) + rk] = r1;
    }
    if ((d4.z >> 13) == xcd) {
      int rk = atomicAdd(&cnt[d4.z], 1);
      if (rk < 64) bins[((size_t)d4.z << 6) + rk] = r2;
    }
    if ((d4.w >> 13) == xcd) {
      int rk = atomicAdd(&cnt[d4.w], 1);
      if (rk < 64) bins[((size_t)d4.w << 6) + rk] = r3;
    }
  }
}

// ---------------- gather: h_out[v] = relu( sum_e XW[src_e, r_e] + XW[v,self] + b ) ---
// Wave per node (4 nodes/block); XCD-swizzled grid (each XCD owns the 8192-node
// range whose bins slice it wrote); all 64 bin slots preloaded in ONE 256B read;
// readlane broadcast; 8/4-deep independent loads. POOL variant fuses the
// per-graph max pool (block's 4 nodes share a graph since 1024 % 4 == 0).
template <bool POOL>
__global__ __launch_bounds__(256) void gather_out(const uint* __restrict__ XWu,
                                                  const uint* __restrict__ bins,
                                                  const int* __restrict__ cnt,
                                                  const float* __restrict__ bias,
                                                  uint* __restrict__ hout,
                                                  ushort* __restrict__ partial2) {
  __shared__ ushort pm[4][128];
  int swz = (blockIdx.x & 7) * 2048 + (blockIdx.x >> 3);  // node-group id
  int node = swz * 4 + (threadIdx.x >> 6);
  int w = threadIdx.x >> 6;
  int ln = threadIdx.x & 63;
  int ne = __builtin_amdgcn_readfirstlane(cnt[node]);
  if (ne > 64) ne = 64;
  // issue self + bias + bin loads early; they complete under the edge loop
  uint sv = XWu[(size_t)node * 576 + 512 + ln];
  float2 bv = ((const float2*)bias)[ln];
  uint mv = bins[((size_t)node << 6) + ln];  // whole bin in one wave read
  float2 acc = {0.f, 0.f};

  int i = 0;
  for (; i + 8 <= ne; i += 8) {
    uint v0 = XWu[(uint)__builtin_amdgcn_readlane((int)mv, i + 0) + ln];
    uint v1 = XWu[(uint)__builtin_amdgcn_readlane((int)mv, i + 1) + ln];
    uint v2 = XWu[(uint)__builtin_amdgcn_readlane((int)mv, i + 2) + ln];
    uint v3 = XWu[(uint)__builtin_amdgcn_readlane((int)mv, i + 3) + ln];
    uint v4 = XWu[(uint)__builtin_amdgcn_readlane((int)mv, i + 4) + ln];
    uint v5 = XWu[(uint)__builtin_amdgcn_readlane((int)mv, i + 5) + ln];
    uint v6 = XWu[(uint)__builtin_amdgcn_readlane((int)mv, i + 6) + ln];
    uint v7 = XWu[(uint)__builtin_amdgcn_readlane((int)mv, i + 7) + ln];
    acc.x += blo(v0); acc.y += bhi(v0);
    acc.x += blo(v1); acc.y += bhi(v1);
    acc.x += blo(v2); acc.y += bhi(v2);
    acc.x += blo(v3); acc.y += bhi(v3);
    acc.x += blo(v4); acc.y += bhi(v4);
    acc.x += blo(v5); acc.y += bhi(v5);
    acc.x += blo(v6); acc.y += bhi(v6);
    acc.x += blo(v7); acc.y += bhi(v7);
  }
  for (; i + 4 <= ne; i += 4) {
    uint v0 = XWu[(uint)__builtin_amdgcn_readlane((int)mv, i + 0) + ln];
    uint v1 = XWu[(uint)__builtin_amdgcn_readlane((int)mv, i + 1) + ln];
    uint v2 = XWu[(uint)__builtin_amdgcn_readlane((int)mv, i + 2) + ln];
    uint v3 = XWu[(uint)__builtin_amdgcn_readlane((int)mv, i + 3) + ln];
    acc.x += blo(v0); acc.y += bhi(v0);
    acc.x += blo(v1); acc.y += bhi(v1);
    acc.x += blo(v2); acc.y += bhi(v2);
    acc.x += blo(v3); acc.y += bhi(v3);
  }
  for (; i < ne; ++i) {
    uint v = XWu[(uint)__builtin_amdgcn_readlane((int)mv, i) + ln];
    acc.x += blo(v); acc.y += bhi(v);
  }

  float r0 = fmaxf(acc.x + blo(sv) + bv.x, 0.f);
  float r1 = fmaxf(acc.y + bhi(sv) + bv.y, 0.f);
  if (POOL) {
    pm[w][ln * 2] = f2b(r0);
    pm[w][ln * 2 + 1] = f2b(r1);
    __syncthreads();
    int t = threadIdx.x;
    if (t < 128) {
      float m = fmaxf(fmaxf(b2f(pm[0][t]), b2f(pm[1][t])),
                      fmaxf(b2f(pm[2][t]), b2f(pm[3][t])));
      partial2[(size_t)swz * 128 + t] = f2b(m);
    }
  } else {
    hout[(size_t)node * 64 + ln] = (uint)f2b(r0) | ((uint)f2b(r1) << 16);
  }
}

// ---------------- classifier: pooled = max over 256 block-partials; out = pooled@Wc+bc
__global__ __launch_bounds__(256) void classify2(const ushort* __restrict__ partial2,
                                                 const float* __restrict__ Wc,
                                                 const float* __restrict__ bc,
                                                 float* __restrict__ out) {
  __shared__ float red[2][128];
  __shared__ float pooled[128];
  int g = blockIdx.x, t = threadIdx.x;
  int d = t & 127, half = t >> 7;
  const ushort* base = partial2 + ((size_t)g * 256 + half * 128) * 128;
  float m = 0.f;
  for (int i = 0; i < 128; ++i) m = fmaxf(m, b2f(base[i * 128 + d]));
  red[half][d] = m;
  __syncthreads();
  if (t < 128) pooled[t] = fmaxf(red[0][t], red[1][t]);
  __syncthreads();
  if (t < 10) {
    float s = bc[t];
    for (int dd = 0; dd < DIM; ++dd) s += pooled[dd] * Wc[dd * 10 + t];
    out[g * 10 + t] = s;
  }
}

extern "C" void kernel_launch(void* const* d_in, const int* in_sizes, int n_in,
                              void* d_out, int out_size, void* d_ws, size_t ws_size,
                              hipStream_t stream) {
  const float* h       = (const float*)d_in[0];
  const float* W1      = (const float*)d_in[1];
  const float* W1_self = (const float*)d_in[2];
  const float* b1      = (const float*)d_in[3];
  const float* W2      = (const float*)d_in[4];
  const float* W2_self = (const float*)d_in[5];
  const float* b2      = (const float*)d_in[6];
  const float* Wc      = (const float*)d_in[7];
  const float* bc      = (const float*)d_in[8];
  const int* src   = (const int*)d_in[9];
  const int* dst   = (const int*)d_in[10];
  const int* etype = (const int*)d_in[11];
  float* out = (float*)d_out;

  char* ws = (char*)d_ws;
  ushort* XW      = (ushort*)(ws);
  ushort* hb      = (ushort*)(ws + 150994944);
  ushort* h1b     = (ushort*)(ws + 167772160);
  ushort* Wt1c    = (ushort*)(ws + 184549376);
  ushort* Wt2c    = (ushort*)(ws + 184844288);
  int*    cnt     = (int*)(ws + 185139200);
  uint*   bins    = (uint*)(ws + 185401344);
  ushort* partial2= (ushort*)(ws + 202178560);

  const int n4_h = N_NODES * DIM / 4;        // 2,097,152
  const int g_h = n4_h / 256;                // 8192
  const int g_gather = N_NODES / 4;          // 16384 (4 waves/block)

  // --- prep ---
  hipMemsetAsync(cnt, 0, N_NODES * sizeof(int), stream);
  f32_to_bf16_vec<<<g_h, 256, 0, stream>>>(h, hb, n4_h);
  wconv_all<<<18, 256, 0, stream>>>(W1, W1_self, W2, W2_self, Wt1c, Wt2c);

  // --- layer 1 GEMM + edge binning, 1:18 interleaved ---
  gemm1_fill<<<G_FUSED, 256, 0, stream>>>(hb, Wt1c, XW, XW_LD,
                                          src, dst, etype, cnt, bins);
  gather_out<false><<<g_gather, 256, 0, stream>>>((const uint*)XW, bins, cnt, b1,
                                                  (uint*)h1b, partial2);

  // --- layer 2: pool fused into gather epilogue; h2 never materialized ---
  gemm_bk64<<<G_GEMM, 256, 0, stream>>>(h1b, Wt2c, XW, XW_LD);
  gather_out<true><<<g_gather, 256, 0, stream>>>((const uint*)XW, bins, cnt, b2,
                                                 (uint*)h1b, partial2);

  // --- classify ---
  classify2<<<N_GRAPHS, 256, 0, stream>>>(partial2, Wc, bc, out);

  (void)in_sizes; (void)n_in; (void)out_size; (void)ws_size;
}

// Round 15
// 219.999 us; speedup vs baseline: 2.3164x; 1.1657x over previous
//
#include <hip/hip_runtime.h>
#include <hip/hip_bf16.h>

// RGCN classifier, MI355X. Round 15: round-12 structure, but fill is hidden
// under the h f32->bf16 conversion in one LDS-free kernel (prep_fill: 3 fill
// blocks : 1 conv block per XCD-aligned group of 32, wconv appended) instead
// of under gemm1 (impossible: fused blocks all reserve the gemm's 32KB LDS,
// and fill needs its full 24576-block concurrency - rounds 11/12/14 evidence).
// gemm1 back to clean standalone. Cores frozen from round 12.
// ws layout (bytes):
//   XW      @ 0          : 65536*1152*2 = 150,994,944  (bf16 [node][1152])
//   hb      @ 150994944  : 16,777,216   (h bf16)
//   h1b     @ 167772160  : 16,777,216
//   Wt1c    @ 184549376  : 294,912      (bf16 [tile*128+n][k])
//   Wt2c    @ 184844288  : 294,912
//   cnt     @ 185139200  : 262,144      (int per node; doubles as degree)
//   bins    @ 185401344  : 16,777,216   (uint [node][64] edge records)
//   partial2@ 202178560  : 4,194,304    (bf16 [16384][128] pool partials)
// total ~206.4 MB

#define N_NODES 65536
#define N_EDGES 786432
#define DIM 128
#define NT 9
#define XW_LD (NT * DIM) /* 1152 */
#define N_GRAPHS 64
#define G_GEMM 4608
#define G_PREP 32786   /* 24576 fill + 8192 conv interleaved + 18 wconv */

typedef unsigned int uint;
typedef unsigned short ushort;
typedef __attribute__((ext_vector_type(8))) short short8;
typedef __attribute__((ext_vector_type(4))) float f32x4;

__device__ inline ushort f2b(float f) {
  uint u = __float_as_uint(f);
  u += 0x7fff + ((u >> 16) & 1);   // RNE
  return (ushort)(u >> 16);
}
__device__ inline float b2f(ushort h) { return __uint_as_float(((uint)h) << 16); }
__device__ inline float blo(uint v) { return __uint_as_float(v << 16); }
__device__ inline float bhi(uint v) { return __uint_as_float(v & 0xffff0000u); }

__device__ inline void gl_lds16(const void* g, void* l) {
  __builtin_amdgcn_global_load_lds(
      (const __attribute__((address_space(1))) unsigned int*)g,
      (__attribute__((address_space(3))) unsigned int*)l, 16, 0, 0);
}

// ---------------- prep: h conversion + weight transpose + edge binning ----------------
// Groups of 32 blocks (XCD-aligned): j = (bid>>3)&3 selects 3 fill : 1 conv.
// fill: slice = bid&7 == physical XCD (cnt/bins slice stays in that XCD's L2);
//       per-slice chunks (group*3+j)*256 edges cover all 786432 edges exactly.
// conv: cid = group*8 + (bid&7) in [0,8192), one float4 per thread.
// wconv: 18 blocks appended at grid tail.
__global__ __launch_bounds__(256) void prep_fill(const float* __restrict__ h,
                                                 ushort* __restrict__ hb,
                                                 const float* __restrict__ W1,
                                                 const float* __restrict__ W1s,
                                                 const float* __restrict__ W2,
                                                 const float* __restrict__ W2s,
                                                 ushort* __restrict__ Wt1,
                                                 ushort* __restrict__ Wt2,
                                                 const int* __restrict__ src,
                                                 const int* __restrict__ dst,
                                                 const int* __restrict__ et,
                                                 int* __restrict__ cnt,
                                                 uint* __restrict__ bins) {
  const int bid = blockIdx.x, tid = threadIdx.x;
  if (bid < 32768) {
    const int group = bid >> 5, j = (bid >> 3) & 3, x = bid & 7;
    if (j < 3) {
      // ---- fill (round-10 structure: 1 edge/thread, full concurrency)
      int e = (group * 3 + j) * 256 + tid;
      int d = dst[e];
      if ((d >> 13) != x) return;
      int r = atomicAdd(&cnt[d], 1);
      if (r < 64) bins[((size_t)d << 6) + r] = (uint)src[e] * 576u + (uint)et[e] * 64u;
    } else {
      // ---- h f32 -> bf16 (pure BW, hides in fill's idle bandwidth)
      int i = (group * 8 + x) * 256 + tid;
      float4 v = ((const float4*)h)[i];
      ushort4 o;
      o.x = f2b(v.x); o.y = f2b(v.y); o.z = f2b(v.z); o.w = f2b(v.w);
      ((ushort4*)hb)[i] = o;
    }
  } else {
    // ---- weights -> bf16 [tile*128+n][k] (tile 8 = W_self)
    int b = bid - 32768;  // 0..17
    const float* S;
    ushort* D;
    int tile;
    if (b < 9) { D = Wt1; tile = b; S = (b < 8) ? (W1 + (size_t)b * 16384) : W1s; }
    else       { D = Wt2; tile = b - 9; S = (tile < 8) ? (W2 + (size_t)tile * 16384) : W2s; }
    for (int i = tid; i < 16384; i += 256) {
      int n = i >> 7, k = i & 127;
      D[((size_t)tile * 128 + n) * 128 + k] = f2b(S[k * 128 + n]);
    }
  }
}

// ---------------- GEMM: XW[65536,1152] = hin[65536,128] @ Wcat ----------------
// 128x128 tile, BK=64 x 2 phases, 32KB LDS, 4 blocks/CU (no accumulator spill).
// XCD swizzle: each XCD owns 64 contiguous bm x all 9 bn. LDS-staged coalesced
// C epilogue (16B/lane full-line writes).
__global__ __launch_bounds__(256, 4) void gemm_bk64(const ushort* __restrict__ A,
                                                    const ushort* __restrict__ Bt,
                                                    ushort* __restrict__ C, int ldc) {
  __shared__ char lds[32768];  // stage: A half-tile @0, B @16384; reused for C
  const int tile = (blockIdx.x & 7) * 576 + (blockIdx.x >> 3);
  const int bm = tile / 9, bn = tile % 9;
  const char* Ag = (const char*)(A + (size_t)bm * 128 * 128);
  const char* Bg = (const char*)(Bt + (size_t)bn * 128 * 128);
  const int tid = threadIdx.x, wv = tid >> 6, ln = tid & 63;
  const int wm = wv >> 1, wn = wv & 1, lr = ln & 15, kq = ln >> 4;

  f32x4 acc[4][4];
#pragma unroll
  for (int m = 0; m < 4; ++m)
#pragma unroll
    for (int n = 0; n < 4; ++n) acc[m][n] = (f32x4){0.f, 0.f, 0.f, 0.f};

#pragma unroll
  for (int kt = 0; kt < 2; ++kt) {
    if (kt) __syncthreads();                  // prior phase's reads done
#pragma unroll
    for (int it = 0; it < 4; ++it) {
      int chunk = it * 4096 + wv * 1024;      // wave-uniform LDS base, 16KB total
      int p = chunk + ln * 16;                // linear lds byte pos
      int row = p >> 7, inb = p & 127;        // 128B rows
      int sw = inb ^ ((row & 7) << 4);        // pre-swizzled global source
      size_t gb = (size_t)row * 256 + (size_t)kt * 128 + sw;
      gl_lds16(Ag + gb, lds + chunk);
      gl_lds16(Bg + gb, lds + 16384 + chunk);
    }
    asm volatile("s_waitcnt vmcnt(0)" ::: "memory");
    __syncthreads();
#pragma unroll
    for (int k2 = 0; k2 < 2; ++k2) {
      const int kb = k2 * 64 + kq * 16;
      short8 a[4], b[4];
#pragma unroll
      for (int m = 0; m < 4; ++m) {
        int row = wm * 64 + m * 16 + lr;
        a[m] = *(const short8*)(lds + ((row * 128 + kb) ^ ((row & 7) << 4)));
      }
#pragma unroll
      for (int n = 0; n < 4; ++n) {
        int col = wn * 64 + n * 16 + lr;
        b[n] = *(const short8*)(lds + 16384 + ((col * 128 + kb) ^ ((col & 7) << 4)));
      }
#pragma unroll
      for (int m = 0; m < 4; ++m)
#pragma unroll
        for (int n = 0; n < 4; ++n)
          acc[m][n] = __builtin_amdgcn_mfma_f32_16x16x32_bf16(a[m], b[n], acc[m][n], 0, 0, 0);
    }
  }

  // ---- epilogue: acc -> LDS bf16 tile [128][256B] (swizzled), then coalesced write
  __syncthreads();  // all stage-buffer reads complete before reuse
#pragma unroll
  for (int m = 0; m < 4; ++m) {
    int rb0 = wm * 64 + m * 16 + kq * 4;
#pragma unroll
    for (int n = 0; n < 4; ++n) {
      int col = wn * 64 + n * 16 + lr;
#pragma unroll
      for (int e = 0; e < 4; ++e) {
        int row = rb0 + e;
        int off = (row * 256 + col * 2) ^ ((row & 7) << 4);
        *(ushort*)(lds + off) = f2b(acc[m][n][e]);
      }
    }
  }
  __syncthreads();
  char* Cg = (char*)C + (size_t)(bm * 128) * (size_t)ldc * 2 + (size_t)bn * 256;
#pragma unroll
  for (int it = 0; it < 8; ++it) {
    int p = it * 4096 + tid * 16;
    int row = p >> 8, inb = p & 255;
    short8 v = *(const short8*)(lds + row * 256 + (inb ^ ((row & 7) << 4)));
    *(short8*)(Cg + (size_t)row * (size_t)ldc * 2 + inb) = v;
  }
}

// ---------------- gather: h_out[v] = relu( sum_e XW[src_e, r_e] + XW[v,self] + b ) ---
// Wave per node (4 nodes/block); all 64 bin slots preloaded in ONE 256B read;
// readlane broadcast; 8/4-deep independent loads. POOL variant fuses the
// per-graph max pool (block's 4 nodes share a graph since 1024 % 4 == 0).
template <bool POOL>
__global__ __launch_bounds__(256) void gather_out(const uint* __restrict__ XWu,
                                                  const uint* __restrict__ bins,
                                                  const int* __restrict__ cnt,
                                                  const float* __restrict__ bias,
                                                  uint* __restrict__ hout,
                                                  ushort* __restrict__ partial2) {
  __shared__ ushort pm[4][128];
  int node = (blockIdx.x * 256 + threadIdx.x) >> 6;
  int w = threadIdx.x >> 6;
  int ln = threadIdx.x & 63;
  int ne = __builtin_amdgcn_readfirstlane(cnt[node]);
  if (ne > 64) ne = 64;
  // issue self + bias + bin loads early; they complete under the edge loop
  uint sv = XWu[(size_t)node * 576 + 512 + ln];
  float2 bv = ((const float2*)bias)[ln];
  uint mv = bins[((size_t)node << 6) + ln];  // whole bin in one wave read
  float2 acc = {0.f, 0.f};

  int i = 0;
  for (; i + 8 <= ne; i += 8) {
    uint v0 = XWu[(uint)__builtin_amdgcn_readlane((int)mv, i + 0) + ln];
    uint v1 = XWu[(uint)__builtin_amdgcn_readlane((int)mv, i + 1) + ln];
    uint v2 = XWu[(uint)__builtin_amdgcn_readlane((int)mv, i + 2) + ln];
    uint v3 = XWu[(uint)__builtin_amdgcn_readlane((int)mv, i + 3) + ln];
    uint v4 = XWu[(uint)__builtin_amdgcn_readlane((int)mv, i + 4) + ln];
    uint v5 = XWu[(uint)__builtin_amdgcn_readlane((int)mv, i + 5) + ln];
    uint v6 = XWu[(uint)__builtin_amdgcn_readlane((int)mv, i + 6) + ln];
    uint v7 = XWu[(uint)__builtin_amdgcn_readlane((int)mv, i + 7) + ln];
    acc.x += blo(v0); acc.y += bhi(v0);
    acc.x += blo(v1); acc.y += bhi(v1);
    acc.x += blo(v2); acc.y += bhi(v2);
    acc.x += blo(v3); acc.y += bhi(v3);
    acc.x += blo(v4); acc.y += bhi(v4);
    acc.x += blo(v5); acc.y += bhi(v5);
    acc.x += blo(v6); acc.y += bhi(v6);
    acc.x += blo(v7); acc.y += bhi(v7);
  }
  for (; i + 4 <= ne; i += 4) {
    uint v0 = XWu[(uint)__builtin_amdgcn_readlane((int)mv, i + 0) + ln];
    uint v1 = XWu[(uint)__builtin_amdgcn_readlane((int)mv, i + 1) + ln];
    uint v2 = XWu[(uint)__builtin_amdgcn_readlane((int)mv, i + 2) + ln];
    uint v3 = XWu[(uint)__builtin_amdgcn_readlane((int)mv, i + 3) + ln];
    acc.x += blo(v0); acc.y += bhi(v0);
    acc.x += blo(v1); acc.y += bhi(v1);
    acc.x += blo(v2); acc.y += bhi(v2);
    acc.x += blo(v3); acc.y += bhi(v3);
  }
  for (; i < ne; ++i) {
    uint v = XWu[(uint)__builtin_amdgcn_readlane((int)mv, i) + ln];
    acc.x += blo(v); acc.y += bhi(v);
  }

  float r0 = fmaxf(acc.x + blo(sv) + bv.x, 0.f);
  float r1 = fmaxf(acc.y + bhi(sv) + bv.y, 0.f);
  if (POOL) {
    pm[w][ln * 2] = f2b(r0);
    pm[w][ln * 2 + 1] = f2b(r1);
    __syncthreads();
    int t = threadIdx.x;
    if (t < 128) {
      float m = fmaxf(fmaxf(b2f(pm[0][t]), b2f(pm[1][t])),
                      fmaxf(b2f(pm[2][t]), b2f(pm[3][t])));
      partial2[(size_t)blockIdx.x * 128 + t] = f2b(m);
    }
  } else {
    hout[(size_t)node * 64 + ln] = (uint)f2b(r0) | ((uint)f2b(r1) << 16);
  }
}

// ---------------- classifier: pooled = max over 256 block-partials; out = pooled@Wc+bc
__global__ __launch_bounds__(256) void classify2(const ushort* __restrict__ partial2,
                                                 const float* __restrict__ Wc,
                                                 const float* __restrict__ bc,
                                                 float* __restrict__ out) {
  __shared__ float red[2][128];
  __shared__ float pooled[128];
  int g = blockIdx.x, t = threadIdx.x;
  int d = t & 127, half = t >> 7;
  const ushort* base = partial2 + ((size_t)g * 256 + half * 128) * 128;
  float m = 0.f;
  for (int i = 0; i < 128; ++i) m = fmaxf(m, b2f(base[i * 128 + d]));
  red[half][d] = m;
  __syncthreads();
  if (t < 128) pooled[t] = fmaxf(red[0][t], red[1][t]);
  __syncthreads();
  if (t < 10) {
    float s = bc[t];
    for (int dd = 0; dd < DIM; ++dd) s += pooled[dd] * Wc[dd * 10 + t];
    out[g * 10 + t] = s;
  }
}

extern "C" void kernel_launch(void* const* d_in, const int* in_sizes, int n_in,
                              void* d_out, int out_size, void* d_ws, size_t ws_size,
                              hipStream_t stream) {
  const float* h       = (const float*)d_in[0];
  const float* W1      = (const float*)d_in[1];
  const float* W1_self = (const float*)d_in[2];
  const float* b1      = (const float*)d_in[3];
  const float* W2      = (const float*)d_in[4];
  const float* W2_self = (const float*)d_in[5];
  const float* b2      = (const float*)d_in[6];
  const float* Wc      = (const float*)d_in[7];
  const float* bc      = (const float*)d_in[8];
  const int* src   = (const int*)d_in[9];
  const int* dst   = (const int*)d_in[10];
  const int* etype = (const int*)d_in[11];
  float* out = (float*)d_out;

  char* ws = (char*)d_ws;
  ushort* XW      = (ushort*)(ws);
  ushort* hb      = (ushort*)(ws + 150994944);
  ushort* h1b     = (ushort*)(ws + 167772160);
  ushort* Wt1c    = (ushort*)(ws + 184549376);
  ushort* Wt2c    = (ushort*)(ws + 184844288);
  int*    cnt     = (int*)(ws + 185139200);
  uint*   bins    = (uint*)(ws + 185401344);
  ushort* partial2= (ushort*)(ws + 202178560);

  const int g_gather = N_NODES / 4;          // 16384 (4 waves/block)

  // --- prep: conversion + weights + edge binning in one LDS-free kernel ---
  hipMemsetAsync(cnt, 0, N_NODES * sizeof(int), stream);
  prep_fill<<<G_PREP, 256, 0, stream>>>(h, hb, W1, W1_self, W2, W2_self,
                                        Wt1c, Wt2c, src, dst, etype, cnt, bins);

  // --- layer 1: XW = hb @ Wcat1 ; h1 = relu(gather + self + b1) ---
  gemm_bk64<<<G_GEMM, 256, 0, stream>>>(hb, Wt1c, XW, XW_LD);
  gather_out<false><<<g_gather, 256, 0, stream>>>((const uint*)XW, bins, cnt, b1,
                                                  (uint*)h1b, partial2);

  // --- layer 2: pool fused into gather epilogue; h2 never materialized ---
  gemm_bk64<<<G_GEMM, 256, 0, stream>>>(h1b, Wt2c, XW, XW_LD);
  gather_out<true><<<g_gather, 256, 0, stream>>>((const uint*)XW, bins, cnt, b2,
                                                 (uint*)h1b, partial2);

  // --- classify ---
  classify2<<<N_GRAPHS, 256, 0, stream>>>(partial2, Wc, bc, out);

  (void)in_sizes; (void)n_in; (void)out_size; (void)ws_size;
}